// Round 9
// baseline (82.702 us; speedup 1.0000x reference)
//
#include <hip/hip_runtime.h>
#include <hip/hip_bf16.h>
#include <math.h>

#define B_ 2
#define L_ 1024
#define D_ 1024
#define H_ 16
#define DH_ 64
#define M_ 64
#define R_ 129
#define NLD ((size_t)B_ * L_ * D_)          // 2,097,152
#define DD  ((size_t)D_ * D_)
#define QSCALE 0.18033688011112042f         // DH^-0.5 * log2(e)

using bf16x8 = __attribute__((ext_vector_type(8))) short;
using f32x4  = __attribute__((ext_vector_type(4))) float;

__device__ __forceinline__ unsigned short f2bf(float f) {
    unsigned int x = __builtin_bit_cast(unsigned int, f);
    unsigned int r = x + 0x7fffu + ((x >> 16) & 1u);   // RNE
    return (unsigned short)(r >> 16);
}
__device__ __forceinline__ float bf2f(unsigned short u) {
    unsigned int x = ((unsigned int)u) << 16;
    return __builtin_bit_cast(float, x);
}
__device__ __forceinline__ unsigned int pk2bf(float lo, float hi) {
    __hip_bfloat162 h = __float22bfloat162_rn(float2{lo, hi});  // v_cvt_pk_bf16_f32 (RNE)
    unsigned int u;
    __builtin_memcpy(&u, &h, 4);
    return u;
}

// ------------------------------------------------------------------
// prep: [0,2048) x->bf16 | [2048,6144) W transposes | [6144,6180) rel tables
// ------------------------------------------------------------------
__global__ __launch_bounds__(256)
void prep(const float* __restrict__ x,
          const float* __restrict__ W0, const float* __restrict__ W1,
          const float* __restrict__ W2, const float* __restrict__ W3,
          const float* __restrict__ relk, const float* __restrict__ relv,
          unsigned short* __restrict__ xb, unsigned short* __restrict__ Wt,
          unsigned short* __restrict__ relkb, unsigned short* __restrict__ relvT)
{
    __shared__ float tile[32][33];
    const int bid = blockIdx.x, t = threadIdx.x;
    if (bid < 2048) {
        const int i = bid * 256 + t;
        float4 v = ((const float4*)x)[i];
        short4 o = { (short)f2bf(v.x), (short)f2bf(v.y), (short)f2bf(v.z), (short)f2bf(v.w) };
        ((short4*)xb)[i] = o;
    } else if (bid < 6144) {
        const int wb = bid - 2048;
        const int z = wb >> 10, rem = wb & 1023;
        const float* W = z == 0 ? W0 : z == 1 ? W1 : z == 2 ? W2 : W3;
        unsigned short* T = Wt + (size_t)z * DD;
        const int k0 = (rem >> 5) * 32, n0 = (rem & 31) * 32;
        const int r = t >> 3, c = (t & 7) * 4;
        float4 v = *(const float4*)&W[(size_t)(k0 + r) * D_ + n0 + c];
        tile[r][c] = v.x; tile[r][c + 1] = v.y; tile[r][c + 2] = v.z; tile[r][c + 3] = v.w;
        __syncthreads();
        short4 o = { (short)f2bf(tile[c][r]),     (short)f2bf(tile[c + 1][r]),
                     (short)f2bf(tile[c + 2][r]), (short)f2bf(tile[c + 3][r]) };
        *(short4*)&T[(size_t)(n0 + r) * D_ + k0 + c] = o;
    } else {
        const int idx = (bid - 6144) * 256 + t;
        if (idx < 144 * 64) {
            const int r = idx >> 6, d = idx & 63;
            relkb[idx] = (r < R_) ? f2bf(relk[r * 64 + d]) : (unsigned short)0;
        }
        if (idx < 64 * 136) {
            const int d = idx / 136, r = idx - d * 136;
            relvT[idx] = (r < R_) ? f2bf(relv[r * 64 + d]) : (unsigned short)0;
        }
    }
}

// ------------------------------------------------------------------
// 64(M)x128(N)-tile bf16 MFMA GEMM, BK=64, 4 waves x 32x64. (unchanged R7)
// ------------------------------------------------------------------
__global__ __launch_bounds__(256)
void gemm64(const unsigned short* __restrict__ A, const unsigned short* __restrict__ Bt,
            unsigned short* __restrict__ Cb, float* __restrict__ Cf, float scale0)
{
    __shared__ unsigned short As[64][64];
    __shared__ unsigned short Bs[128][64];

    const int t = threadIdx.x, lane = t & 63, wid = t >> 6;
    const int fr = lane & 15, g = lane >> 4;
    const int m0 = blockIdx.y * 64;
    const int nglob = blockIdx.x * 128;
    const int mat = nglob >> 10;
    const int n0 = nglob & 1023;
    const float scale = (mat == 0) ? scale0 : 1.f;
    const int wm = (wid >> 1) * 32, wn = (wid & 1) * 64;

    f32x4 acc[2][4] = {};

    int arow[2], akof[2], adst[2];
#pragma unroll
    for (int c = 0; c < 2; ++c) {
        const int chunk = c * 256 + t;
        arow[c] = chunk >> 3;
        akof[c] = ((chunk & 7) ^ (arow[c] & 7)) * 8;
        adst[c] = chunk * 8;
    }
    int brow[4], bkof[4], bdst[4];
#pragma unroll
    for (int c = 0; c < 4; ++c) {
        const int chunk = c * 256 + t;
        brow[c] = chunk >> 3;
        bkof[c] = ((chunk & 7) ^ (brow[c] & 7)) * 8;
        bdst[c] = chunk * 8;
    }

    const unsigned short* Abase = A  + (size_t)m0 * D_;
    const unsigned short* Bbase = Bt + (size_t)nglob * D_;

    for (int k0 = 0; k0 < D_; k0 += 64) {
        __syncthreads();
#pragma unroll
        for (int c = 0; c < 2; ++c)
            __builtin_amdgcn_global_load_lds(
                (const __attribute__((address_space(1))) void*)(Abase + (size_t)arow[c] * D_ + k0 + akof[c]),
                (__attribute__((address_space(3))) void*)(&As[0][0] + adst[c]), 16, 0, 0);
#pragma unroll
        for (int c = 0; c < 4; ++c)
            __builtin_amdgcn_global_load_lds(
                (const __attribute__((address_space(1))) void*)(Bbase + (size_t)brow[c] * D_ + k0 + bkof[c]),
                (__attribute__((address_space(3))) void*)(&Bs[0][0] + bdst[c]), 16, 0, 0);
        __syncthreads();

#pragma unroll
        for (int kb = 0; kb < 2; ++kb) {
            bf16x8 av[2], bv[4];
#pragma unroll
            for (int i = 0; i < 2; ++i) {
                const int ra = wm + i * 16 + fr;
                av[i] = *(const bf16x8*)&As[ra][(((kb << 2) + g) ^ (ra & 7)) * 8];
            }
#pragma unroll
            for (int j = 0; j < 4; ++j) {
                const int rb = wn + j * 16 + fr;
                bv[j] = *(const bf16x8*)&Bs[rb][(((kb << 2) + g) ^ (rb & 7)) * 8];
            }
#pragma unroll
            for (int i = 0; i < 2; ++i)
#pragma unroll
                for (int j = 0; j < 4; ++j)
                    acc[i][j] = __builtin_amdgcn_mfma_f32_16x16x32_bf16(av[i], bv[j], acc[i][j], 0, 0, 0);
        }
    }

    const int orow = g * 4;
    if (Cb) {
        unsigned short* Cp = Cb + (size_t)mat * NLD;
#pragma unroll
        for (int i = 0; i < 2; ++i)
#pragma unroll
            for (int j = 0; j < 4; ++j) {
                unsigned short* cp = Cp + (size_t)(m0 + wm + i * 16 + orow) * D_ + n0 + wn + j * 16 + fr;
#pragma unroll
                for (int rg = 0; rg < 4; ++rg)
                    cp[(size_t)rg * D_] = f2bf(acc[i][j][rg] * scale);
            }
    } else {
#pragma unroll
        for (int i = 0; i < 2; ++i)
#pragma unroll
            for (int j = 0; j < 4; ++j) {
                float* cp = Cf + (size_t)(m0 + wm + i * 16 + orow) * D_ + n0 + wn + j * 16 + fr;
#pragma unroll
                for (int rg = 0; rg < 4; ++rg)
                    cp[(size_t)rg * D_] = acc[i][j][rg] * scale;
            }
    }
}

// ------------------------------------------------------------------
// MFMA flash attention, 32 q-rows/block, 1024 blocks (4/CU, 4 waves/SIMD).
// Waves: wr = row-half (16 rows), wj = j-half (32 of 64 KV cols).
// ------------------------------------------------------------------
__device__ __forceinline__ void stage_k(const unsigned short* src, unsigned short* dst, int t)
{
#pragma unroll
    for (int it = 0; it < 2; ++it) {
        const int c = it * 256 + t;
        const int j = c >> 3;
        const int sc = (c & 7) ^ (j & 7);
        __builtin_amdgcn_global_load_lds(
            (const __attribute__((address_space(1))) void*)(src + (size_t)j * D_ + sc * 8),
            (__attribute__((address_space(3))) void*)(dst + c * 8), 16, 0, 0);
    }
}

__device__ __forceinline__ void write_vt(unsigned short (*Vtl)[64], int jp, int d0, bf16x8 a, bf16x8 b)
{
    const int jlo = (2 * jp) & 7;
    const int jc  = jp >> 2;
#pragma unroll
    for (int e = 0; e < 8; ++e) {
        const int d = d0 + e;
        const unsigned int val = (unsigned int)(unsigned short)a[e]
                               | ((unsigned int)(unsigned short)b[e] << 16);
        *(unsigned int*)&Vtl[d][((jc ^ (d & 7)) << 3) + jlo] = val;
    }
}

__global__ __launch_bounds__(256)
void attn_mfma(const unsigned short* __restrict__ Qb, const unsigned short* __restrict__ Kb,
               const unsigned short* __restrict__ Vb,
               const unsigned short* __restrict__ relkb,   // [144][64] bf16
               const unsigned short* __restrict__ relvT,   // [64][136] bf16
               const float* __restrict__ relv,             // [129][64] f32
               unsigned short* __restrict__ Ob)
{
    __shared__ unsigned short Klds[2][64][64];   // 16 KB (dbuf, DMA); f32 scratch at epilogue
    __shared__ unsigned short Vt[64][64];        // 8 KB (single, reg-staged)
    __shared__ unsigned short Plds[32][88];      // 5.5 KB (two 32-col windows @ 40)
    __shared__ unsigned short QW[32][136];       // 8.5 KB (QR -> wsum in place)
    __shared__ float lred[2][32], p0red[2][32], p128red[2][32];

    const int t    = threadIdx.x;
    const int lane = t & 63;
    const int w    = t >> 6;
    const int fr   = lane & 15;
    const int g    = lane >> 4;
    const int wr   = w & 1;      // row half
    const int wj   = w >> 1;     // j half

    const int bx  = blockIdx.x;
    const int xcd = bx & 7, slot = bx >> 3;
    const int bh  = (xcd << 2) | (slot >> 5);
    const int rb  = slot & 31;
    const int b   = bh >> 4, h = bh & 15;
    const int i0  = rb * 32;
    const size_t head = (size_t)b * L_ * D_ + (size_t)h * DH_;

    const int iloc = wr * 16 + fr;           // q-row within block [0,32)
    const int ig   = i0 + iloc;              // global q-row

    const unsigned short* Kh = Kb + head;
    const unsigned short* Vh = Vb + head;

    stage_k(Kh, &Klds[0][0][0], t);

    const int jp = t & 31, d0v = ((t >> 5) & 7) * 8;
    bf16x8 va  = *(const bf16x8*)(Vh + (size_t)(2 * jp) * D_ + d0v);
    bf16x8 vb2 = *(const bf16x8*)(Vh + (size_t)(2 * jp + 1) * D_ + d0v);

    bf16x8 qf[2];
    {
        const unsigned short* qp = Qb + head + (size_t)ig * D_;
        qf[0] = *(const bf16x8*)(qp + g * 8);
        qf[1] = *(const bf16x8*)(qp + 32 + g * 8);
    }

    // QR^T = relk @ q^T -> QW cols (rc split across wj)
    auto qr_block = [&](int rc) {
        f32x4 acc = {};
#pragma unroll
        for (int kb = 0; kb < 2; ++kb) {
            bf16x8 rv = *(const bf16x8*)&relkb[(size_t)(rc * 16 + fr) * 64 + kb * 32 + g * 8];
            acc = __builtin_amdgcn_mfma_f32_16x16x32_bf16(rv, qf[kb], acc, 0, 0, 0);
        }
        if (rc < 8) {
            uint2 pk = { pk2bf(acc[0], acc[1]), pk2bf(acc[2], acc[3]) };
            *(uint2*)&QW[iloc][rc * 16 + g * 4] = pk;
        } else if (g == 0) {
            QW[iloc][128] = f2bf(acc[0]);
        }
    };
    if (wj == 0) { qr_block(0); qr_block(1); qr_block(2); qr_block(3); qr_block(8); }
    else         { qr_block(4); qr_block(5); qr_block(6); qr_block(7); }

    // zero interior cols that no (i,j) visit will overwrite (stale QR would
    // leak into the wsum@relv MFMA). low cols (<=62) live in wj=0's rc range,
    // high cols (>=65) in wj=1's -> same-wave ordering, no race.
    {
        const int lo_end = 63 - ig;            // stale [1, lo_end] (rb 0/1)
        const int hi_beg = 1088 - ig;          // stale [hi_beg, 127] (rb 30/31)
        if (wj == 0) {
            for (int c = 1 + g; c <= lo_end; c += 4) QW[iloc][c] = 0;
        } else {
            for (int c = hi_beg + g; c <= 127; c += 4) QW[iloc][c] = 0;
        }
    }

    write_vt(Vt, jp, d0v, va, vb2);
    asm volatile("s_waitcnt vmcnt(0)" ::: "memory");
    __syncthreads();

    const float qr0   = bf2f(QW[iloc][0]);
    const float qr128 = bf2f(QW[iloc][128]);

    f32x4 oacc[4] = {};
    float lpart = 0.f, pe0p = 0.f, pe128p = 0.f;

    int bb = 0;
    for (int jt = 0; jt < 16; ++jt) {
        const bool pre = (jt < 15);
        if (pre) {
            stage_k(Kh + (size_t)(jt + 1) * 64 * D_, &Klds[bb ^ 1][0][0], t);
            const unsigned short* vp = Vh + (size_t)((jt + 1) * 64 + 2 * jp) * D_ + d0v;
            va  = *(const bf16x8*)vp;
            vb2 = *(const bf16x8*)(vp + D_);
        }

        // ---- S^T = K @ Q^T : wave's j-window = jt*64 + wj*32 .. +31 ----
        f32x4 s[2];
        __builtin_amdgcn_s_setprio(1);
#pragma unroll
        for (int fc = 0; fc < 2; ++fc) {
            f32x4 a = {};
            const int j = wj * 32 + fc * 16 + fr;
#pragma unroll
            for (int kb = 0; kb < 2; ++kb) {
                bf16x8 kv = *(const bf16x8*)&Klds[bb][j][(((kb << 2) + g) ^ (j & 7)) * 8];
                a = __builtin_amdgcn_mfma_f32_16x16x32_bf16(kv, qf[kb], a, 0, 0, 0);
            }
            s[fc] = a;
        }
        __builtin_amdgcn_s_setprio(0);

        // ---- V^T fragments (k = wave's 32-j window) ----
        bf16x8 vv[4];
#pragma unroll
        for (int fd = 0; fd < 4; ++fd) {
            const int d = fd * 16 + fr;
            vv[fd] = *(const bf16x8*)&Vt[d][(((wj << 2) + g) ^ (d & 7)) * 8];
        }

        // ---- softmax: u = window offset in 32-units ----
        const int u     = 2 * jt + wj - rb;
        const int cbase = 32 * u - iloc + g * 4 + 64;   // col for (fc=0, reg=0)

        if (u <= -3 || u >= 3) {
            // FAR: whole window one boundary class
            const float qrc = (u < 0) ? qr0 : qr128;
            float tsum = 0.f;
#pragma unroll
            for (int fc = 0; fc < 2; ++fc) {
                float p0 = exp2f(s[fc][0] + qrc);
                float p1 = exp2f(s[fc][1] + qrc);
                float p2 = exp2f(s[fc][2] + qrc);
                float p3 = exp2f(s[fc][3] + qrc);
                uint2 pk = { pk2bf(p0, p1), pk2bf(p2, p3) };
                *(uint2*)&Plds[iloc][wj * 40 + fc * 16 + g * 4] = pk;
                tsum += (p0 + p1) + (p2 + p3);
            }
            lpart += tsum;
            if (u < 0) pe0p += tsum; else pe128p += tsum;
        } else if (u >= -1 && u <= 1) {
            // INTERIOR: cols in [1,127], read bias then overwrite with weight
#pragma unroll
            for (int fc = 0; fc < 2; ++fc) {
                const int c0 = cbase + fc * 16;
                float pe[4];
#pragma unroll
                for (int reg = 0; reg < 4; ++reg) {
                    pe[reg] = exp2f(s[fc][reg] + bf2f(QW[iloc][c0 + reg]));
                    lpart += pe[reg];
                }
                uint2 pk = { pk2bf(pe[0], pe[1]), pk2bf(pe[2], pe[3]) };
                *(uint2*)&Plds[iloc][wj * 40 + fc * 16 + g * 4] = pk;
                QW[iloc][c0 + 0] = (unsigned short)(pk.x & 0xffffu);
                QW[iloc][c0 + 1] = (unsigned short)(pk.x >> 16);
                QW[iloc][c0 + 2] = (unsigned short)(pk.y & 0xffffu);
                QW[iloc][c0 + 3] = (unsigned short)(pk.y >> 16);
            }
        } else {
            // EDGE (u = ±2): clamped col, routed accumulation
#pragma unroll
            for (int fc = 0; fc < 2; ++fc) {
                float pe[4];
#pragma unroll
                for (int reg = 0; reg < 4; ++reg) {
                    const int colr = cbase + fc * 16 + reg;
                    const int col  = colr < 0 ? 0 : (colr > 128 ? 128 : colr);
                    const float bias = (col == 0) ? qr0 : (col == 128) ? qr128
                                                        : bf2f(QW[iloc][col]);
                    pe[reg] = exp2f(s[fc][reg] + bias);
                    lpart += pe[reg];
                    if (col == 0)        pe0p   += pe[reg];
                    else if (col == 128) pe128p += pe[reg];
                    else                 QW[iloc][col] = f2bf(pe[reg]);
                }
                uint2 pk = { pk2bf(pe[0], pe[1]), pk2bf(pe[2], pe[3]) };
                *(uint2*)&Plds[iloc][wj * 40 + fc * 16 + g * 4] = pk;
            }
        }

        asm volatile("s_waitcnt lgkmcnt(0)" ::: "memory");
        __builtin_amdgcn_sched_barrier(0);

        // ---- PV: one MFMA per fd (k = 32-j window) ----
        bf16x8 pa = *(const bf16x8*)&Plds[iloc][wj * 40 + g * 8];
        __builtin_amdgcn_s_setprio(1);
#pragma unroll
        for (int fd = 0; fd < 4; ++fd)
            oacc[fd] = __builtin_amdgcn_mfma_f32_16x16x32_bf16(pa, vv[fd], oacc[fd], 0, 0, 0);
        __builtin_amdgcn_s_setprio(0);

        if (pre) {
            asm volatile("s_waitcnt lgkmcnt(0)" ::: "memory");
            __builtin_amdgcn_s_barrier();          // Vt reads done; keep K-DMA in flight
            write_vt(Vt, jp, d0v, va, vb2);
        }
        asm volatile("s_waitcnt vmcnt(0)" ::: "memory");
        __syncthreads();
        bb ^= 1;
    }

    // ---- reduce partials: across g (shfl), then across wj (LDS) ----
    lpart  += __shfl_xor(lpart, 16);  lpart  += __shfl_xor(lpart, 32);
    pe0p   += __shfl_xor(pe0p, 16);   pe0p   += __shfl_xor(pe0p, 32);
    pe128p += __shfl_xor(pe128p, 16); pe128p += __shfl_xor(pe128p, 32);
    if (lane < 16) {
        lred[wj][iloc]    = lpart;
        p0red[wj][iloc]   = pe0p;
        p128red[wj][iloc] = pe128p;
    }
    __syncthreads();
    const float lt    = lred[0][iloc]    + lred[1][iloc];
    const float p0t   = p0red[0][iloc]   + p0red[1][iloc];
    const float p128t = p128red[0][iloc] + p128red[1][iloc];
    if (wj == 0 && g == 0) {
        QW[iloc][0]   = f2bf(p0t);
        QW[iloc][128] = f2bf(p128t);
    }
    asm volatile("s_waitcnt lgkmcnt(0)" ::: "memory");
    __syncthreads();

    // ---- o += wsum @ relv (kc split across wj; col 128 scalar later) ----
#pragma unroll
    for (int kk = 0; kk < 2; ++kk) {
        const int kc = wj * 2 + kk;
        bf16x8 wa = *(const bf16x8*)&QW[iloc][kc * 32 + g * 8];
#pragma unroll
        for (int fd = 0; fd < 4; ++fd) {
            bf16x8 rv = *(const bf16x8*)&relvT[(size_t)(fd * 16 + fr) * 136 + kc * 32 + g * 8];
            oacc[fd] = __builtin_amdgcn_mfma_f32_16x16x32_bf16(wa, rv, oacc[fd], 0, 0, 0);
        }
    }

    // redistribute lt/p128t from row-lane (fr) to C-layout rows (g*4+reg)
    float invd[4], pr128[4];
#pragma unroll
    for (int reg = 0; reg < 4; ++reg) {
        const int src = (lane & 48) | (g * 4 + reg);
        invd[reg]  = 1.f / __shfl(lt, src, 64);
        pr128[reg] = __shfl(p128t, src, 64);
    }

    // ---- combine oacc across wj via Klds-as-f32 scratch; wj=1 writes out ----
    float* Of = (float*)&Klds[0][0][0];   // 8 KB needed, 16 KB available
    if (wj == 0) {
#pragma unroll
        for (int fd = 0; fd < 4; ++fd)
#pragma unroll
            for (int reg = 0; reg < 4; ++reg)
                Of[(wr * 16 + g * 4 + reg) * 64 + fd * 16 + fr] = oacc[fd][reg];
    }
    __syncthreads();
    if (wj == 1) {
#pragma unroll
        for (int fd = 0; fd < 4; ++fd) {
            const float r128 = relv[128 * 64 + fd * 16 + fr];
            unsigned short* op = Ob + head + (size_t)(i0 + wr * 16 + g * 4) * D_ + fd * 16 + fr;
#pragma unroll
            for (int reg = 0; reg < 4; ++reg) {
                const float val = oacc[fd][reg]
                                + Of[(wr * 16 + g * 4 + reg) * 64 + fd * 16 + fr]
                                + pr128[reg] * r128;
                op[(size_t)reg * D_] = f2bf(val * invd[reg]);
            }
        }
    }
}

// ------------------------------------------------------------------
extern "C" void kernel_launch(void* const* d_in, const int* in_sizes, int n_in,
                              void* d_out, int out_size, void* d_ws, size_t ws_size,
                              hipStream_t stream)
{
    const float* x    = (const float*)d_in[0];
    const float* Wq   = (const float*)d_in[1];
    const float* Wk   = (const float*)d_in[2];
    const float* Wv   = (const float*)d_in[3];
    const float* Wo   = (const float*)d_in[4];
    const float* relk = (const float*)d_in[5];
    const float* relv = (const float*)d_in[6];
    float* out = (float*)d_out;

    unsigned short* xb    = (unsigned short*)d_ws;
    unsigned short* Wt    = xb + NLD;
    unsigned short* relkb = Wt + 4 * DD;
    unsigned short* relvT = relkb + 144 * 64;
    unsigned short* QKVb  = relvT + 64 * 136;
    unsigned short* Ob    = QKVb + 3 * NLD;

    prep<<<dim3(6180), 256, 0, stream>>>(x, Wq, Wk, Wv, Wo, relk, relv, xb, Wt, relkb, relvT);

    gemm64<<<dim3(24, 32), 256, 0, stream>>>(xb, Wt, QKVb, nullptr, QSCALE);   // Q,K,V fused

    attn_mfma<<<dim3(1024), 256, 0, stream>>>(QKVb, QKVb + NLD, QKVb + 2 * NLD,
                                              relkb, relvT, relv, Ob);

    gemm64<<<dim3(8, 32), 256, 0, stream>>>(Ob, Wt + 3 * DD, nullptr, out, 1.f);
}